// Round 15
// baseline (490.754 us; speedup 1.0000x reference)
//
#include <hip/hip_runtime.h>

#define N_NODES 50000
#define N_EDGES 800000
#define IN_DIM 768
#define HIDDEN 256
#define N_CLASSES 10
#define N_GRAPHS 128

typedef __attribute__((ext_vector_type(8))) short bf16x8;
typedef __attribute__((ext_vector_type(4))) float f32x4;
typedef __attribute__((ext_vector_type(8))) unsigned short u16x8;

__device__ __forceinline__ float bf2f(unsigned short u) {
    union { unsigned int i; float f; } c; c.i = ((unsigned int)u) << 16; return c.f;
}
__device__ __forceinline__ unsigned short f2bf(float f) {
    unsigned int x = __float_as_uint(f);
    return (unsigned short)((x + 0x7fffu + ((x >> 16) & 1u)) >> 16);  // RNE
}

// ---------------- CSR build ----------------
__global__ void zero_int(int* p, int n) {
    int i = blockIdx.x * blockDim.x + threadIdx.x;
    if (i < n) p[i] = 0;
}

__global__ void zero_f32(float* p, int n) {
    int i = blockIdx.x * blockDim.x + threadIdx.x;
    if (i < n) p[i] = 0.f;
}

__global__ void hist_dst(const int* __restrict__ dst, int* __restrict__ cnt) {
    int e = blockIdx.x * blockDim.x + threadIdx.x;
    if (e < N_EDGES) atomicAdd(&cnt[dst[e]], 1);
}

// single-block exclusive scan (shfl-based) + fused dinv = rsqrt(1+cnt)
__global__ __launch_bounds__(1024) void scan_kernel(const int* __restrict__ cnt,
                                                    int* __restrict__ rowstart,
                                                    int* __restrict__ cursor,
                                                    float* __restrict__ dinv) {
    __shared__ int wsum[16];
    __shared__ int chunk_carry;
    const int tid = threadIdx.x, lane = tid & 63, wid = tid >> 6;
    if (tid == 0) chunk_carry = 0;
    __syncthreads();
    for (int base = 0; base < N_NODES; base += 1024) {
        int i = base + tid;
        int v = (i < N_NODES) ? cnt[i] : 0;
        if (i < N_NODES) dinv[i] = rsqrtf(1.0f + (float)v);
        int s = v;
#pragma unroll
        for (int d = 1; d < 64; d <<= 1) { int t = __shfl_up(s, d); if (lane >= d) s += t; }
        if (lane == 63) wsum[wid] = s;
        __syncthreads();
        if (tid < 16) {
            int ww = wsum[tid];
#pragma unroll
            for (int d = 1; d < 16; d <<= 1) { int t = __shfl_up(ww, d); if (tid >= d) ww += t; }
            wsum[tid] = ww;
        }
        __syncthreads();
        int wpre = (wid == 0) ? 0 : wsum[wid - 1];
        int excl = chunk_carry + wpre + s - v;
        if (i < N_NODES) { rowstart[i] = excl; cursor[i] = excl; }
        int total = wsum[15];
        __syncthreads();
        if (tid == 0) chunk_carry += total;
        __syncthreads();
    }
    if (threadIdx.x == 0) rowstart[N_NODES] = chunk_carry;
}

__global__ void scatter_edges(const int* __restrict__ src, const int* __restrict__ dst,
                              int* __restrict__ cursor, int* __restrict__ col) {
    int e = blockIdx.x * blockDim.x + threadIdx.x;
    if (e >= N_EDGES) return;
    int d = dst[e];
    int pos = atomicAdd(&cursor[d], 1);
    col[pos] = src[e];
}

// ---------------- W [K][256] fp32 -> WT [256][K] bf16, LDS-tiled ----------------
__global__ __launch_bounds__(256) void transpose_w_bf16(const float* __restrict__ W,
                                                        unsigned short* __restrict__ WT, int K) {
    __shared__ float t[32][33];
    int tx = threadIdx.x & 31, ty = threadIdx.x >> 5;  // 8 row-groups
    int k0 = blockIdx.x * 32, n0 = blockIdx.y * 32;
#pragma unroll
    for (int i = 0; i < 4; ++i) {
        int k = k0 + ty + i * 8;
        t[ty + i * 8][tx] = W[(size_t)k * 256 + n0 + tx];
    }
    __syncthreads();
#pragma unroll
    for (int i = 0; i < 4; ++i) {
        int n = n0 + ty + i * 8;
        WT[(size_t)n * K + k0 + tx] = f2bf(t[tx][ty + i * 8]);
    }
}

// ---------------- MFMA GEMM: C[M,256](bf16) = A[M,K] * BT[256,K]^T ----
// A-panel-stationary: 32 A-rows x FULL K staged to LDS once (1 barrier total),
// then a barrier-free K-loop: A frags from LDS (XOR-swizzled), B frags loaded
// directly global->VGPR (B is 393KB, L2-resident, shared by all blocks).
// 4 waves split N: wave w owns cols [64w, 64w+64). Swapped-operand mfma(B,A):
// C row = lane&15, col = 64w + 16f + 4*(lane>>4) + reg.
// LDS granule col swizzle: within each 8-granule (128B) group, col ^= (row&7).
template <int K, bool CVT>
__global__ __launch_bounds__(256, 4) void gemm_mfma(const void* __restrict__ Av,
                                                    const unsigned short* __restrict__ BT,
                                                    unsigned short* __restrict__ C, int M) {
    constexpr int NG = K / 8;                 // granules per row (16B bf16 each)
    __shared__ uint4 As[32 * NG];             // conv1: 48 KB, conv2: 16 KB
    const int tid = threadIdx.x;
    const int lane = tid & 63, w = tid >> 6;
    const int lr = lane & 15, kg = lane >> 4;
    const int bm = blockIdx.x * 32;

    // ---- stage A panel (once) ----
    if constexpr (CVT) {
        const float* Af = (const float*)Av;
#pragma unroll
        for (int i = 0; i < (32 * NG) / 256; ++i) {
            int glin = i * 256 + tid;
            int r = glin / NG, c = glin % NG;
            int rg = bm + r; rg = rg < M ? rg : M - 1;
            const float* p = &Af[(size_t)rg * K + c * 8];
            float4 u = *(const float4*)p;
            float4 v = *(const float4*)(p + 4);
            u16x8 o;
            o[0] = f2bf(u.x); o[1] = f2bf(u.y); o[2] = f2bf(u.z); o[3] = f2bf(u.w);
            o[4] = f2bf(v.x); o[5] = f2bf(v.y); o[6] = f2bf(v.z); o[7] = f2bf(v.w);
            int csw = (c & ~7) | ((c & 7) ^ (r & 7));
            *(u16x8*)&As[r * NG + csw] = o;
        }
    } else {
        const unsigned short* Ab = (const unsigned short*)Av;
#pragma unroll
        for (int i = 0; i < (32 * NG) / 256; ++i) {
            int glin = i * 256 + tid;
            int r = glin / NG, c = glin % NG;
            int rg = bm + r; rg = rg < M ? rg : M - 1;
            uint4 v = *(const uint4*)&Ab[(size_t)rg * K + c * 8];
            int csw = (c & ~7) | ((c & 7) ^ (r & 7));
            As[r * NG + csw] = v;
        }
    }
    __syncthreads();  // the only barrier

    // ---- barrier-free K-loop ----
    f32x4 acc[2][4] = {};
    const int r0 = lr, r1 = 16 + lr;
    const unsigned short* Brow0 = &BT[(size_t)(64 * w + lr) * K];

    for (int g0 = 0; g0 < NG; g0 += 8) {
#pragma unroll
        for (int h = 0; h < 2; ++h) {
            int gc = 4 * h + kg;
            bf16x8 a0 = *(const bf16x8*)&As[r0 * NG + g0 + (gc ^ (r0 & 7))];
            bf16x8 a1 = *(const bf16x8*)&As[r1 * NG + g0 + (gc ^ (r1 & 7))];
            int koff = (g0 + gc) * 8;
#pragma unroll
            for (int f = 0; f < 4; ++f) {
                bf16x8 bf = *(const bf16x8*)&Brow0[(size_t)(16 * f) * K + koff];
                acc[0][f] = __builtin_amdgcn_mfma_f32_16x16x32_bf16(bf, a0, acc[0][f], 0, 0, 0);
                acc[1][f] = __builtin_amdgcn_mfma_f32_16x16x32_bf16(bf, a1, acc[1][f], 0, 0, 0);
            }
        }
    }

    // ---- epilogue ----
#pragma unroll
    for (int m = 0; m < 2; ++m) {
        int orow = bm + 16 * m + lr;
        if (orow < M) {
#pragma unroll
            for (int f = 0; f < 4; ++f) {
                ushort4 o = make_ushort4(f2bf(acc[m][f][0]), f2bf(acc[m][f][1]),
                                         f2bf(acc[m][f][2]), f2bf(acc[m][f][3]));
                *(ushort4*)&C[(size_t)orow * 256 + 64 * w + 16 * f + 4 * kg] = o;
            }
        }
    }
}

// ---------------- CSR aggregation: 16B gathers, 2 edges per wave-step ------
template <bool RELU, bool OUTBF>
__global__ __launch_bounds__(256) void agg_csr(const unsigned short* __restrict__ h,
                                               const float* __restrict__ dinv,
                                               const int* __restrict__ rowstart,
                                               const int* __restrict__ col,
                                               const float* __restrict__ bias,
                                               void* __restrict__ outv) {
    int node = (blockIdx.x * 256 + threadIdx.x) >> 6;
    if (node >= N_NODES) return;
    const int lane = threadIdx.x & 63;
    const int half = lane >> 5, sl = lane & 31;

    float dd = dinv[node];
    float acc[8] = {};

    // self term (half 0 only contributes; half 1 loads same line, weight 0)
    {
        u16x8 hv = *(const u16x8*)&h[(size_t)node * 256 + sl * 8];
        float wgt = half ? 0.f : dd * dd;
#pragma unroll
        for (int i = 0; i < 8; ++i) acc[i] += bf2f(hv[i]) * wgt;
    }

    int j0 = rowstart[node], jend = rowstart[node + 1];
    for (int j = j0; j < jend; j += 2) {
        int sidx = j + half;
        bool p = sidx < jend;
        int s = p ? col[sidx] : node;
        float nrm = p ? dinv[s] * dd : 0.f;
        u16x8 v = *(const u16x8*)&h[(size_t)s * 256 + sl * 8];
#pragma unroll
        for (int i = 0; i < 8; ++i) acc[i] += bf2f(v[i]) * nrm;
    }

    // merge halves
#pragma unroll
    for (int i = 0; i < 8; ++i) acc[i] += __shfl_xor(acc[i], 32);

    if (half == 0) {
        float4 b0 = *(const float4*)&bias[sl * 8];
        float4 b1 = *(const float4*)&bias[sl * 8 + 4];
        acc[0] += b0.x; acc[1] += b0.y; acc[2] += b0.z; acc[3] += b0.w;
        acc[4] += b1.x; acc[5] += b1.y; acc[6] += b1.z; acc[7] += b1.w;
        if (RELU) {
#pragma unroll
            for (int i = 0; i < 8; ++i) acc[i] = fmaxf(acc[i], 0.f);
        }
        if (OUTBF) {
            u16x8 o;
#pragma unroll
            for (int i = 0; i < 8; ++i) o[i] = f2bf(acc[i]);
            *(u16x8*)((unsigned short*)outv + (size_t)node * 256 + sl * 8) = o;
        } else {
            float* ob = (float*)outv + (size_t)node * 256 + sl * 8;
            *(float4*)ob = make_float4(acc[0], acc[1], acc[2], acc[3]);
            *(float4*)(ob + 4) = make_float4(acc[4], acc[5], acc[6], acc[7]);
        }
    }
}

// ---------------- parallel segmented pooling ----------------
#define POOL_CHUNK 49
__global__ __launch_bounds__(256) void pool_partial(const float* __restrict__ x,
                                                    const int* __restrict__ batch,
                                                    float* __restrict__ gsum) {
    int lo = blockIdx.x * POOL_CHUNK;
    if (lo >= N_NODES) return;
    int hi = lo + POOL_CHUNK; if (hi > N_NODES) hi = N_NODES;
    int c = threadIdx.x;
    int g = batch[lo];
    float acc = 0.f;
    for (int n = lo; n < hi; ++n) {
        int gn = batch[n];
        if (gn != g) { atomicAdd(&gsum[g * 256 + c], acc); acc = 0.f; g = gn; }
        acc += x[(size_t)n * 256 + c];
    }
    atomicAdd(&gsum[g * 256 + c], acc);
}

// ---------------- FC head (graph bounds via in-kernel binary search) --------
__global__ __launch_bounds__(256) void fc_head(const float* __restrict__ gsum,
                                               const int* __restrict__ batch,
                                               const float* __restrict__ Wfc,
                                               const float* __restrict__ bfc,
                                               float* __restrict__ out) {
    int g = blockIdx.x;
    int c = threadIdx.x;
    int lo = 0, hi = N_NODES;
    while (lo < hi) { int m = (lo + hi) >> 1; if (batch[m] < g) lo = m + 1; else hi = m; }
    int lo2 = lo, hi2 = N_NODES;
    while (lo2 < hi2) { int m = (lo2 + hi2) >> 1; if (batch[m] < g + 1) lo2 = m + 1; else hi2 = m; }
    float inv = 1.0f / fmaxf((float)(lo2 - lo), 1.0f);
    __shared__ float pooled[256];
    pooled[c] = gsum[(size_t)g * 256 + c] * inv;
    __syncthreads();
    if (c < N_CLASSES) {
        float acc = bfc[c];
        for (int k = 0; k < 256; ++k) acc += pooled[k] * Wfc[k * N_CLASSES + c];
        out[g * N_CLASSES + c] = acc;
    }
}

extern "C" void kernel_launch(void* const* d_in, const int* in_sizes, int n_in,
                              void* d_out, int out_size, void* d_ws, size_t ws_size,
                              hipStream_t stream) {
    const float* emb  = (const float*)d_in[0];
    const int*   eidx = (const int*)d_in[1];
    const int*   batch= (const int*)d_in[2];
    const float* W1   = (const float*)d_in[3];
    const float* b1   = (const float*)d_in[4];
    const float* W2   = (const float*)d_in[5];
    const float* b2   = (const float*)d_in[6];
    const float* Wfc  = (const float*)d_in[7];
    const float* bfc  = (const float*)d_in[8];
    float* out = (float*)d_out;

    const int* src = eidx;
    const int* dst = eidx + N_EDGES;

    char* ws = (char*)d_ws;
    size_t off = 0;
    auto alloc = [&](size_t bytes) { void* p = ws + off; off += (bytes + 1023) & ~(size_t)1023; return p; };
    int*   rowcnt   = (int*)alloc(N_NODES * 4);
    int*   rowstart = (int*)alloc((N_NODES + 1) * 4);
    int*   cursor   = (int*)alloc(N_NODES * 4);
    int*   col      = (int*)alloc(N_EDGES * 4);
    float* dinv     = (float*)alloc(N_NODES * 4);
    float* gsum     = (float*)alloc((size_t)N_GRAPHS * 256 * 4);
    unsigned short* W1T = (unsigned short*)alloc((size_t)HIDDEN * IN_DIM * 2);   // [256][768]
    unsigned short* W2T = (unsigned short*)alloc((size_t)HIDDEN * HIDDEN * 2);   // [256][256]
    unsigned short* bufH = (unsigned short*)alloc((size_t)N_NODES * 256 * 2);    // h (bf16)
    unsigned short* x1 = (unsigned short*)alloc((size_t)N_NODES * 256 * 2);      // bf16
    float* x2 = (float*)alloc((size_t)N_NODES * 256 * 4);                        // f32

    const int NB = (N_NODES + 255) / 256;
    const int EBk = (N_EDGES + 255) / 256;
    const int AGG_B = (N_NODES * 64 + 255) / 256;  // 12500
    dim3 gemm_grid((N_NODES + 31) / 32, 1);        // 1563 blocks
    const int POOL_B = (N_NODES + POOL_CHUNK - 1) / POOL_CHUNK;  // 1021

    // CSR + norm
    zero_int<<<NB, 256, 0, stream>>>(rowcnt, N_NODES);
    hist_dst<<<EBk, 256, 0, stream>>>(dst, rowcnt);
    scan_kernel<<<1, 1024, 0, stream>>>(rowcnt, rowstart, cursor, dinv);
    scatter_edges<<<EBk, 256, 0, stream>>>(src, dst, cursor, col);
    zero_f32<<<(N_GRAPHS * 256 + 255) / 256, 256, 0, stream>>>(gsum, N_GRAPHS * 256);

    // weight transposes (bf16)
    transpose_w_bf16<<<dim3(IN_DIM / 32, 8), 256, 0, stream>>>(W1, W1T, IN_DIM);
    transpose_w_bf16<<<dim3(HIDDEN / 32, 8), 256, 0, stream>>>(W2, W2T, HIDDEN);

    // conv1: h1 = emb @ W1 (f32 A converted in-staging), then agg -> x1 (bf16, relu)
    gemm_mfma<IN_DIM, true><<<gemm_grid, 256, 0, stream>>>(emb, W1T, bufH, N_NODES);
    agg_csr<true, true><<<AGG_B, 256, 0, stream>>>(bufH, dinv, rowstart, col, b1, x1);

    // conv2: h2 = x1 @ W2, then agg -> x2 (f32)
    gemm_mfma<HIDDEN, false><<<gemm_grid, 256, 0, stream>>>(x1, W2T, bufH, N_NODES);
    agg_csr<false, false><<<AGG_B, 256, 0, stream>>>(bufH, dinv, rowstart, col, b2, x2);

    // pool + head
    pool_partial<<<POOL_B, 256, 0, stream>>>(x2, batch, gsum);
    fc_head<<<N_GRAPHS, 256, 0, stream>>>(gsum, batch, Wfc, bfc, out);
}

// Round 16
// 396.376 us; speedup vs baseline: 1.2381x; 1.2381x over previous
//
#include <hip/hip_runtime.h>

#define N_NODES 50000
#define N_EDGES 800000
#define IN_DIM 768
#define HIDDEN 256
#define N_CLASSES 10
#define N_GRAPHS 128

typedef __attribute__((ext_vector_type(8))) short bf16x8;
typedef __attribute__((ext_vector_type(4))) float f32x4;
typedef __attribute__((ext_vector_type(8))) unsigned short u16x8;

__device__ __forceinline__ float bf2f(unsigned short u) {
    union { unsigned int i; float f; } c; c.i = ((unsigned int)u) << 16; return c.f;
}
__device__ __forceinline__ unsigned short f2bf(float f) {
    unsigned int x = __float_as_uint(f);
    return (unsigned short)((x + 0x7fffu + ((x >> 16) & 1u)) >> 16);  // RNE
}

// async global->LDS, 16B per lane; LDS dest = uniform base + lane*16
__device__ __forceinline__ void gload16(const void* g, void* l) {
    __builtin_amdgcn_global_load_lds((const __attribute__((address_space(1))) void*)g,
                                     (__attribute__((address_space(3))) void*)l, 16, 0, 0);
}

// ---------------- CSR build ----------------
__global__ void zero_int(int* p, int n) {
    int i = blockIdx.x * blockDim.x + threadIdx.x;
    if (i < n) p[i] = 0;
}

__global__ void zero_f32(float* p, int n) {
    int i = blockIdx.x * blockDim.x + threadIdx.x;
    if (i < n) p[i] = 0.f;
}

__global__ void hist_dst(const int* __restrict__ dst, int* __restrict__ cnt) {
    int e = blockIdx.x * blockDim.x + threadIdx.x;
    if (e < N_EDGES) atomicAdd(&cnt[dst[e]], 1);
}

// single-block exclusive scan (shfl-based) + fused dinv = rsqrt(1+cnt)
__global__ __launch_bounds__(1024) void scan_kernel(const int* __restrict__ cnt,
                                                    int* __restrict__ rowstart,
                                                    int* __restrict__ cursor,
                                                    float* __restrict__ dinv) {
    __shared__ int wsum[16];
    __shared__ int chunk_carry;
    const int tid = threadIdx.x, lane = tid & 63, wid = tid >> 6;
    if (tid == 0) chunk_carry = 0;
    __syncthreads();
    for (int base = 0; base < N_NODES; base += 1024) {
        int i = base + tid;
        int v = (i < N_NODES) ? cnt[i] : 0;
        if (i < N_NODES) dinv[i] = rsqrtf(1.0f + (float)v);
        int s = v;
#pragma unroll
        for (int d = 1; d < 64; d <<= 1) { int t = __shfl_up(s, d); if (lane >= d) s += t; }
        if (lane == 63) wsum[wid] = s;
        __syncthreads();
        if (tid < 16) {
            int ww = wsum[tid];
#pragma unroll
            for (int d = 1; d < 16; d <<= 1) { int t = __shfl_up(ww, d); if (tid >= d) ww += t; }
            wsum[tid] = ww;
        }
        __syncthreads();
        int wpre = (wid == 0) ? 0 : wsum[wid - 1];
        int excl = chunk_carry + wpre + s - v;
        if (i < N_NODES) { rowstart[i] = excl; cursor[i] = excl; }
        int total = wsum[15];
        __syncthreads();
        if (tid == 0) chunk_carry += total;
        __syncthreads();
    }
    if (threadIdx.x == 0) rowstart[N_NODES] = chunk_carry;
}

__global__ void scatter_edges(const int* __restrict__ src, const int* __restrict__ dst,
                              int* __restrict__ cursor, int* __restrict__ col) {
    int e = blockIdx.x * blockDim.x + threadIdx.x;
    if (e >= N_EDGES) return;
    int d = dst[e];
    int pos = atomicAdd(&cursor[d], 1);
    col[pos] = src[e];
}

// ---------------- W [K][256] fp32 -> WT [256][K] bf16, LDS-tiled ----------------
__global__ __launch_bounds__(256) void transpose_w_bf16(const float* __restrict__ W,
                                                        unsigned short* __restrict__ WT, int K) {
    __shared__ float t[32][33];
    int tx = threadIdx.x & 31, ty = threadIdx.x >> 5;  // 8 row-groups
    int k0 = blockIdx.x * 32, n0 = blockIdx.y * 32;
#pragma unroll
    for (int i = 0; i < 4; ++i) {
        int k = k0 + ty + i * 8;
        t[ty + i * 8][tx] = W[(size_t)k * 256 + n0 + tx];
    }
    __syncthreads();
#pragma unroll
    for (int i = 0; i < 4; ++i) {
        int n = n0 + ty + i * 8;
        WT[(size_t)n * K + k0 + tx] = f2bf(t[tx][ty + i * 8]);
    }
}

// ---------------- MFMA GEMM: C[M,256](bf16) = A[M,K] * BT[256,K]^T ----
// tile 64x256, BK=64, 4 waves (wave w owns rows [16w,16w+16)), grid ceil(M/64).
// DOUBLE-BUFFERED pipeline, ONE barrier per K-step:
//   [barrier] -> issue B(k+1) gload_lds + A(k+1) reg-loads -> MFMA on buf[cur]
//   -> cvt+ds_write A(k+1) into buf[nxt] -> [barrier]
// so the vmcnt(0) drain at the barrier lands ~MFMA-phase after load issue.
// A reg-staged (CVT: f32->bf16 in-flight); B via global_load_lds (linear dest,
// pre-swizzled per-lane source). LDS slot [r][g] holds source granule g^(r&7).
template <int K, bool CVT>
__global__ __launch_bounds__(256, 2) void gemm_mfma(const void* __restrict__ Av,
                                                    const unsigned short* __restrict__ BT,
                                                    unsigned short* __restrict__ C, int M) {
    constexpr int NS = K / 64;
    __shared__ uint4 sm[5120];   // 80 KB: As[2][512] (8KB each), Bs[2][2048] (32KB each)
    uint4* As = sm;
    uint4* Bs = sm + 1024;
    const int tid = threadIdx.x;
    const int lane = tid & 63, w = tid >> 6;
    const int lr = lane & 15, kg = lane >> 4;
    const int bm = blockIdx.x * 64;

    // A staging geometry: thread covers granules (ra, ca) and (ra, ca+1)
    const int ra = tid >> 2;          // 0..63
    const int ca = (tid & 3) * 2;     // 0,2,4,6
    int rga = bm + ra; rga = rga < M ? rga : M - 1;

    f32x4 acc[16] = {};

    // ---- prologue: stage step 0 ----
    {
        if constexpr (CVT) {
            const float* p = &((const float*)Av)[(size_t)rga * K + ca * 8];
            float4 u0 = ((const float4*)p)[0], u1 = ((const float4*)p)[1];
            float4 u2 = ((const float4*)p)[2], u3 = ((const float4*)p)[3];
            u16x8 o0, o1;
            o0[0] = f2bf(u0.x); o0[1] = f2bf(u0.y); o0[2] = f2bf(u0.z); o0[3] = f2bf(u0.w);
            o0[4] = f2bf(u1.x); o0[5] = f2bf(u1.y); o0[6] = f2bf(u1.z); o0[7] = f2bf(u1.w);
            o1[0] = f2bf(u2.x); o1[1] = f2bf(u2.y); o1[2] = f2bf(u2.z); o1[3] = f2bf(u2.w);
            o1[4] = f2bf(u3.x); o1[5] = f2bf(u3.y); o1[6] = f2bf(u3.z); o1[7] = f2bf(u3.w);
            *(u16x8*)&As[ra * 8 + (ca ^ (ra & 7))] = o0;
            *(u16x8*)&As[ra * 8 + ((ca + 1) ^ (ra & 7))] = o1;
        } else {
            const unsigned short* Ab = (const unsigned short*)Av;
            uint4 v0 = *(const uint4*)&Ab[(size_t)rga * K + ca * 8];
            uint4 v1 = *(const uint4*)&Ab[(size_t)rga * K + ca * 8 + 8];
            As[ra * 8 + (ca ^ (ra & 7))] = v0;
            As[ra * 8 + ((ca + 1) ^ (ra & 7))] = v1;
        }
#pragma unroll
        for (int i = 0; i < 8; ++i) {
            int glin = w * 512 + i * 64 + lane;
            int n = glin >> 3, g = glin & 7;
            int gs = g ^ (n & 7);
            gload16(&BT[(size_t)n * K + gs * 8], &Bs[w * 512 + i * 64]);
        }
    }
    __syncthreads();

    // ---- pipelined K-loop ----
    for (int k = 0; k < NS; ++k) {
        const int cur = k & 1, nxt = cur ^ 1;
        const int kk1 = (k + 1) * 64;
        float4 u0, u1, u2, u3;
        uint4 v0, v1;
        if (k + 1 < NS) {
            // issue B(k+1) async stage
#pragma unroll
            for (int i = 0; i < 8; ++i) {
                int glin = w * 512 + i * 64 + lane;
                int n = glin >> 3, g = glin & 7;
                int gs = g ^ (n & 7);
                gload16(&BT[(size_t)n * K + kk1 + gs * 8], &Bs[nxt * 2048 + w * 512 + i * 64]);
            }
            // issue A(k+1) reg loads
            if constexpr (CVT) {
                const float* p = &((const float*)Av)[(size_t)rga * K + kk1 + ca * 8];
                u0 = ((const float4*)p)[0]; u1 = ((const float4*)p)[1];
                u2 = ((const float4*)p)[2]; u3 = ((const float4*)p)[3];
            } else {
                const unsigned short* Ab = (const unsigned short*)Av;
                v0 = *(const uint4*)&Ab[(size_t)rga * K + kk1 + ca * 8];
                v1 = *(const uint4*)&Ab[(size_t)rga * K + kk1 + ca * 8 + 8];
            }
        }
        // MFMA phase on buf[cur]
#pragma unroll
        for (int h = 0; h < 2; ++h) {
            int r0 = 16 * w + lr;
            int gc = 4 * h + kg;
            bf16x8 a0 = *(const bf16x8*)&As[cur * 512 + r0 * 8 + (gc ^ (r0 & 7))];
#pragma unroll
            for (int f = 0; f < 16; ++f) {
                int nr = 16 * f + lr;
                bf16x8 bf = *(const bf16x8*)&Bs[cur * 2048 + nr * 8 + (gc ^ (nr & 7))];
                acc[f] = __builtin_amdgcn_mfma_f32_16x16x32_bf16(bf, a0, acc[f], 0, 0, 0);
            }
        }
        // write A(k+1) into buf[nxt] (loads landed under the MFMA phase)
        if (k + 1 < NS) {
            if constexpr (CVT) {
                u16x8 o0, o1;
                o0[0] = f2bf(u0.x); o0[1] = f2bf(u0.y); o0[2] = f2bf(u0.z); o0[3] = f2bf(u0.w);
                o0[4] = f2bf(u1.x); o0[5] = f2bf(u1.y); o0[6] = f2bf(u1.z); o0[7] = f2bf(u1.w);
                o1[0] = f2bf(u2.x); o1[1] = f2bf(u2.y); o1[2] = f2bf(u2.z); o1[3] = f2bf(u2.w);
                o1[4] = f2bf(u3.x); o1[5] = f2bf(u3.y); o1[6] = f2bf(u3.z); o1[7] = f2bf(u3.w);
                *(u16x8*)&As[nxt * 512 + ra * 8 + (ca ^ (ra & 7))] = o0;
                *(u16x8*)&As[nxt * 512 + ra * 8 + ((ca + 1) ^ (ra & 7))] = o1;
            } else {
                As[nxt * 512 + ra * 8 + (ca ^ (ra & 7))] = v0;
                As[nxt * 512 + ra * 8 + ((ca + 1) ^ (ra & 7))] = v1;
            }
        }
        __syncthreads();
    }

    // ---- epilogue: swapped layout -> lane lr = out row, col = 16f + 4kg ----
    int orow = bm + 16 * w + lr;
    if (orow < M) {
#pragma unroll
        for (int f = 0; f < 16; ++f) {
            ushort4 o = make_ushort4(f2bf(acc[f][0]), f2bf(acc[f][1]),
                                     f2bf(acc[f][2]), f2bf(acc[f][3]));
            *(ushort4*)&C[(size_t)orow * 256 + 16 * f + 4 * kg] = o;
        }
    }
}

// ---------------- CSR aggregation: 16B gathers, 2 halves x 4-deep MLP ------
// one wave per dst node; lanes 0-31 = even edges, lanes 32-63 = odd edges;
// 4 independent gathers in flight per half; cross-half merge via shfl_xor(32).
template <bool RELU, bool OUTBF>
__global__ __launch_bounds__(256) void agg_csr(const unsigned short* __restrict__ h,
                                               const float* __restrict__ dinv,
                                               const int* __restrict__ rowstart,
                                               const int* __restrict__ col,
                                               const float* __restrict__ bias,
                                               void* __restrict__ outv) {
    int node = (blockIdx.x * 256 + threadIdx.x) >> 6;
    if (node >= N_NODES) return;
    const int lane = threadIdx.x & 63;
    const int half = lane >> 5, sl = lane & 31;

    float dd = dinv[node];
    float acc[8] = {};

    // self term (half 0 only contributes; half 1 loads same line, weight 0)
    {
        u16x8 hv = *(const u16x8*)&h[(size_t)node * 256 + sl * 8];
        float wgt = half ? 0.f : dd * dd;
#pragma unroll
        for (int i = 0; i < 8; ++i) acc[i] += bf2f(hv[i]) * wgt;
    }

    int j0 = rowstart[node], jend = rowstart[node + 1];
    int j = j0;
    // 8 edges per iteration: half h takes j+h, j+2+h, j+4+h, j+6+h -> 4 loads in flight
    for (; j + 8 <= jend; j += 8) {
        int s0 = col[j + half];
        int s1 = col[j + 2 + half];
        int s2 = col[j + 4 + half];
        int s3 = col[j + 6 + half];
        float n0 = dinv[s0] * dd, n1 = dinv[s1] * dd;
        float n2 = dinv[s2] * dd, n3 = dinv[s3] * dd;
        u16x8 v0 = *(const u16x8*)&h[(size_t)s0 * 256 + sl * 8];
        u16x8 v1 = *(const u16x8*)&h[(size_t)s1 * 256 + sl * 8];
        u16x8 v2 = *(const u16x8*)&h[(size_t)s2 * 256 + sl * 8];
        u16x8 v3 = *(const u16x8*)&h[(size_t)s3 * 256 + sl * 8];
#pragma unroll
        for (int i = 0; i < 8; ++i)
            acc[i] += bf2f(v0[i]) * n0 + bf2f(v1[i]) * n1 + bf2f(v2[i]) * n2 + bf2f(v3[i]) * n3;
    }
    // tail: 2 edges per iteration, predicated
    for (; j < jend; j += 2) {
        int sidx = j + half;
        bool p = sidx < jend;
        int s = p ? col[sidx] : node;
        float nrm = p ? dinv[s] * dd : 0.f;
        u16x8 v = *(const u16x8*)&h[(size_t)s * 256 + sl * 8];
#pragma unroll
        for (int i = 0; i < 8; ++i) acc[i] += bf2f(v[i]) * nrm;
    }

    // merge halves
#pragma unroll
    for (int i = 0; i < 8; ++i) acc[i] += __shfl_xor(acc[i], 32);

    if (half == 0) {
        float4 b0 = *(const float4*)&bias[sl * 8];
        float4 b1 = *(const float4*)&bias[sl * 8 + 4];
        acc[0] += b0.x; acc[1] += b0.y; acc[2] += b0.z; acc[3] += b0.w;
        acc[4] += b1.x; acc[5] += b1.y; acc[6] += b1.z; acc[7] += b1.w;
        if (RELU) {
#pragma unroll
            for (int i = 0; i < 8; ++i) acc[i] = fmaxf(acc[i], 0.f);
        }
        if (OUTBF) {
            u16x8 o;
#pragma unroll
            for (int i = 0; i < 8; ++i) o[i] = f2bf(acc[i]);
            *(u16x8*)((unsigned short*)outv + (size_t)node * 256 + sl * 8) = o;
        } else {
            float* ob = (float*)outv + (size_t)node * 256 + sl * 8;
            *(float4*)ob = make_float4(acc[0], acc[1], acc[2], acc[3]);
            *(float4*)(ob + 4) = make_float4(acc[4], acc[5], acc[6], acc[7]);
        }
    }
}

// ---------------- parallel segmented pooling ----------------
#define POOL_CHUNK 49
__global__ __launch_bounds__(256) void pool_partial(const float* __restrict__ x,
                                                    const int* __restrict__ batch,
                                                    float* __restrict__ gsum) {
    int lo = blockIdx.x * POOL_CHUNK;
    if (lo >= N_NODES) return;
    int hi = lo + POOL_CHUNK; if (hi > N_NODES) hi = N_NODES;
    int c = threadIdx.x;
    int g = batch[lo];
    float acc = 0.f;
    for (int n = lo; n < hi; ++n) {
        int gn = batch[n];
        if (gn != g) { atomicAdd(&gsum[g * 256 + c], acc); acc = 0.f; g = gn; }
        acc += x[(size_t)n * 256 + c];
    }
    atomicAdd(&gsum[g * 256 + c], acc);
}

// ---------------- FC head (graph bounds via in-kernel binary search) --------
__global__ __launch_bounds__(256) void fc_head(const float* __restrict__ gsum,
                                               const int* __restrict__ batch,
                                               const float* __restrict__ Wfc,
                                               const float* __restrict__ bfc,
                                               float* __restrict__ out) {
    int g = blockIdx.x;
    int c = threadIdx.x;
    int lo = 0, hi = N_NODES;
    while (lo < hi) { int m = (lo + hi) >> 1; if (batch[m] < g) lo = m + 1; else hi = m; }
    int lo2 = lo, hi2 = N_NODES;
    while (lo2 < hi2) { int m = (lo2 + hi2) >> 1; if (batch[m] < g + 1) lo2 = m + 1; else hi2 = m; }
    float inv = 1.0f / fmaxf((float)(lo2 - lo), 1.0f);
    __shared__ float pooled[256];
    pooled[c] = gsum[(size_t)g * 256 + c] * inv;
    __syncthreads();
    if (c < N_CLASSES) {
        float acc = bfc[c];
        for (int k = 0; k < 256; ++k) acc += pooled[k] * Wfc[k * N_CLASSES + c];
        out[g * N_CLASSES + c] = acc;
    }
}

extern "C" void kernel_launch(void* const* d_in, const int* in_sizes, int n_in,
                              void* d_out, int out_size, void* d_ws, size_t ws_size,
                              hipStream_t stream) {
    const float* emb  = (const float*)d_in[0];
    const int*   eidx = (const int*)d_in[1];
    const int*   batch= (const int*)d_in[2];
    const float* W1   = (const float*)d_in[3];
    const float* b1   = (const float*)d_in[4];
    const float* W2   = (const float*)d_in[5];
    const float* b2   = (const float*)d_in[6];
    const float* Wfc  = (const float*)d_in[7];
    const float* bfc  = (const float*)d_in[8];
    float* out = (float*)d_out;

    const int* src = eidx;
    const int* dst = eidx + N_EDGES;

    char* ws = (char*)d_ws;
    size_t off = 0;
    auto alloc = [&](size_t bytes) { void* p = ws + off; off += (bytes + 1023) & ~(size_t)1023; return p; };
    int*   rowcnt   = (int*)alloc(N_NODES * 4);
    int*   rowstart = (int*)alloc((N_NODES + 1) * 4);
    int*   cursor   = (int*)alloc(N_NODES * 4);
    int*   col      = (int*)alloc(N_EDGES * 4);
    float* dinv     = (float*)alloc(N_NODES * 4);
    float* gsum     = (float*)alloc((size_t)N_GRAPHS * 256 * 4);
    unsigned short* W1T = (unsigned short*)alloc((size_t)HIDDEN * IN_DIM * 2);   // [256][768]
    unsigned short* W2T = (unsigned short*)alloc((size_t)HIDDEN * HIDDEN * 2);   // [256][256]
    unsigned short* bufH = (unsigned short*)alloc((size_t)N_NODES * 256 * 2);    // h (bf16)
    unsigned short* x1 = (unsigned short*)alloc((size_t)N_NODES * 256 * 2);      // bf16
    float* x2 = (float*)alloc((size_t)N_NODES * 256 * 4);                        // f32

    const int NB = (N_NODES + 255) / 256;
    const int EBk = (N_EDGES + 255) / 256;
    const int AGG_B = (N_NODES * 64 + 255) / 256;  // 12500
    dim3 gemm_grid((N_NODES + 63) / 64, 1);        // 782 blocks, full N per block
    const int POOL_B = (N_NODES + POOL_CHUNK - 1) / POOL_CHUNK;  // 1021

    // CSR + norm
    zero_int<<<NB, 256, 0, stream>>>(rowcnt, N_NODES);
    hist_dst<<<EBk, 256, 0, stream>>>(dst, rowcnt);
    scan_kernel<<<1, 1024, 0, stream>>>(rowcnt, rowstart, cursor, dinv);
    scatter_edges<<<EBk, 256, 0, stream>>>(src, dst, cursor, col);
    zero_f32<<<(N_GRAPHS * 256 + 255) / 256, 256, 0, stream>>>(gsum, N_GRAPHS * 256);

    // weight transposes (bf16)
    transpose_w_bf16<<<dim3(IN_DIM / 32, 8), 256, 0, stream>>>(W1, W1T, IN_DIM);
    transpose_w_bf16<<<dim3(HIDDEN / 32, 8), 256, 0, stream>>>(W2, W2T, HIDDEN);

    // conv1: h1 = emb @ W1 (f32 A converted in-staging), then agg -> x1 (bf16, relu)
    gemm_mfma<IN_DIM, true><<<gemm_grid, 256, 0, stream>>>(emb, W1T, bufH, N_NODES);
    agg_csr<true, true><<<AGG_B, 256, 0, stream>>>(bufH, dinv, rowstart, col, b1, x1);

    // conv2: h2 = x1 @ W2, then agg -> x2 (f32)
    gemm_mfma<HIDDEN, false><<<gemm_grid, 256, 0, stream>>>(x1, W2T, bufH, N_NODES);
    agg_csr<false, false><<<AGG_B, 256, 0, stream>>>(bufH, dinv, rowstart, col, b2, x2);

    // pool + head
    pool_partial<<<POOL_B, 256, 0, stream>>>(x2, batch, gsum);
    fc_head<<<N_GRAPHS, 256, 0, stream>>>(gsum, batch, Wfc, bfc, out);
}